// Round 11
// baseline (489.097 us; speedup 1.0000x reference)
//
#include <hip/hip_runtime.h>
#include <hip/hip_bf16.h>
#include <hip/hip_cooperative_groups.h>

// RoIAlign (avg, aligned=True).
//   input: (4, 256, 200, 200) fp32, rois: (1024, 5) fp32 -> out (1024,256,7,7) fp32
//
// R11 (resubmitted R12–R14 after infra failures — never yet measured):
// FUSED single cooperative kernel (phase A: fp32->grouped bf16 transform,
// grid.sync, phase B: branchless 16-tap gather). Derived from measured facts:
// both R4 kernels individually < 97.7 us (absent from top-5 which is all
// ~100 us harness ws-poison fills), so the two-pass work is < 196 us of the
// 296 us total. Fusion removes the inter-kernel full-drain barrier + launch
// gap, pins panel (b,g) production AND consumption to the same XCD (g = xcd
// for both phases -> intermediate never crosses an XCD L2), and guarantees
// the fused kernel tops the profile next round for counter visibility.
// Phase bodies are bit-identical to R4 (absmax 0.015625 passed).

#define CCH 256
#define FH 200
#define FW 200
#define N_ROIS 1024
#define PP 49          // 7*7 bins
#define NG 8           // channel groups (256/32)
#define GSZ 32         // channels per group
#define PLANE (FH*FW)

namespace cg = cooperative_groups;

__device__ __forceinline__ void fma8q(float* acc, uint4 q, float w)
{
    unsigned short u[8];
    __builtin_memcpy(u, &q, 16);
    #pragma unroll
    for (int j = 0; j < 8; ++j)
        acc[j] = fmaf(w, __uint_as_float((unsigned)u[j] << 16), acc[j]);
}

// ---------------- fused cooperative kernel ----------------
// grid = 1024 blocks x 256 thr; 4 blocks/CU co-resident (<=128 VGPR).
// xcd = blockIdx.x & 7 (round-robin dispatch); local = blockIdx.x >> 3 in [0,128).
__global__ __launch_bounds__(256, 4) void fused_roi_align(
    const float* __restrict__ in,
    const float* __restrict__ rois,
    unsigned short* __restrict__ gfeat,
    int* __restrict__ perm,
    float* __restrict__ out)
{
    const int t     = threadIdx.x;
    const int xcd   = blockIdx.x & 7;
    const int local = blockIdx.x >> 3;

    // ---- ROI counting-sort by image index (block 0 only; consumed after sync)
    if (blockIdx.x == 0) {
        __shared__ int cnt[4];
        __shared__ int base[4];
        if (t < 4) cnt[t] = 0;
        __syncthreads();
        int bb[4], po[4];
        #pragma unroll
        for (int r = 0; r < 4; ++r) {
            int ri = r * 256 + t;
            int b = (int)rois[ri * 5];
            bb[r] = b;
            po[r] = atomicAdd(&cnt[b], 1);
        }
        __syncthreads();
        if (t == 0) {
            int s = 0;
            #pragma unroll
            for (int i = 0; i < 4; ++i) { base[i] = s; s += cnt[i]; }
        }
        __syncthreads();
        #pragma unroll
        for (int r = 0; r < 4; ++r)
            perm[base[bb[r]] + po[r]] = r * 256 + t;
    }

    // ---- phase A: transform panels (b, g=xcd), b = 0..3 ----
    // per-XCD item space: i in [0, 4*PLANE); b = i/PLANE, p = i%PLANE.
    for (int i = local * 256 + t; i < 4 * PLANE; i += 128 * 256) {
        int b  = i / PLANE;
        int p  = i - b * PLANE;
        int bg = (b << 3) + xcd;
        const float* src = in + (size_t)bg * GSZ * PLANE + p;

        unsigned short tmp[GSZ];
        #pragma unroll
        for (int j = 0; j < GSZ; ++j) {
            float f = __builtin_nontemporal_load(&src[(size_t)j * PLANE]);
            unsigned u = __float_as_uint(f);
            tmp[j] = (unsigned short)((u + 0x7FFFu + ((u >> 16) & 1u)) >> 16); // RNE
        }
        uint4* dst = (uint4*)(gfeat + ((size_t)bg * PLANE + p) * GSZ);
        #pragma unroll
        for (int k = 0; k < 4; ++k) {
            uint4 q;
            __builtin_memcpy(&q, &tmp[k * 8], 16);
            dst[k] = q;
        }
    }

    cg::this_grid().sync();

    // ---- phase B: gather, g = xcd (reads only panels this XCD wrote) ----
    // per-XCD item space: i in [0, N_ROIS*PP*4); s = i&3, bin = (i>>2)%49,
    // n_slot = (i>>2)/49 (sorted order -> b sweeps 0..3 monotonically).
    const int g = xcd;
    for (int i = local * 256 + t; i < N_ROIS * PP * 4; i += 128 * 256) {
        int s      = i & 3;
        int bin    = (i >> 2) % PP;
        int n_slot = (i >> 2) / PP;
        int n      = perm[n_slot];
        int ph = bin / 7, pw = bin % 7;

        const float* roi = rois + n * 5;
        int   b  = (int)roi[0];
        float x1 = roi[1] * 0.25f - 0.5f;
        float y1 = roi[2] * 0.25f - 0.5f;
        float x2 = roi[3] * 0.25f - 0.5f;
        float y2 = roi[4] * 0.25f - 0.5f;
        float bin_h = (y2 - y1) / 7.0f;
        float bin_w = (x2 - x1) / 7.0f;

        const unsigned short* plane =
            gfeat + (size_t)(b * NG + g) * (size_t)PLANE * GSZ + s * 8;

        int   yy0[2], yy1[2];
        float wy0[2], wy1[2];
        #pragma unroll
        for (int iy = 0; iy < 2; ++iy) {
            float y = y1 + ((float)ph + ((float)iy + 0.5f) * 0.5f) * bin_h;
            float v = (y >= -1.0f && y <= (float)FH) ? 1.0f : 0.0f;
            float yc = fminf(fmaxf(y, 0.0f), (float)(FH - 1));
            int   y0 = (int)yc;
            yy0[iy] = y0;
            yy1[iy] = min(y0 + 1, FH - 1);
            float ly = yc - (float)y0;
            wy1[iy] = ly * v;
            wy0[iy] = (1.0f - ly) * v;
        }
        int   xx0[2], xx1[2];
        float wx0[2], wx1[2];
        #pragma unroll
        for (int ix = 0; ix < 2; ++ix) {
            float x = x1 + ((float)pw + ((float)ix + 0.5f) * 0.5f) * bin_w;
            float v = (x >= -1.0f && x <= (float)FW) ? 1.0f : 0.0f;
            float xc = fminf(fmaxf(x, 0.0f), (float)(FW - 1));
            int   x0 = (int)xc;
            xx0[ix] = x0;
            xx1[ix] = min(x0 + 1, FW - 1);
            float lx = xc - (float)x0;
            wx1[ix] = lx * v;
            wx0[ix] = (1.0f - lx) * v;
        }

        float acc[8] = {0, 0, 0, 0, 0, 0, 0, 0};

        #pragma unroll
        for (int iy = 0; iy < 2; ++iy) {
            const unsigned short* r0 = plane + (size_t)(yy0[iy] * FW) * GSZ;
            const unsigned short* r1 = plane + (size_t)(yy1[iy] * FW) * GSZ;
            #pragma unroll
            for (int ix = 0; ix < 2; ++ix) {
                uint4 qA = *(const uint4*)(r0 + (size_t)xx0[ix] * GSZ);
                uint4 qB = *(const uint4*)(r0 + (size_t)xx1[ix] * GSZ);
                uint4 qC = *(const uint4*)(r1 + (size_t)xx0[ix] * GSZ);
                uint4 qD = *(const uint4*)(r1 + (size_t)xx1[ix] * GSZ);
                fma8q(acc, qA, wy0[iy] * wx0[ix]);
                fma8q(acc, qB, wy0[iy] * wx1[ix]);
                fma8q(acc, qC, wy1[iy] * wx0[ix]);
                fma8q(acc, qD, wy1[iy] * wx1[ix]);
            }
        }

        float* o = out + ((size_t)n * CCH + g * GSZ + s * 8) * PP + bin;
        #pragma unroll
        for (int j = 0; j < 8; ++j)
            __builtin_nontemporal_store(acc[j] * 0.25f, o + j * PP);
    }
}

// ---------------- R4 two-kernel path (fallback if coop launch refused) ------
__global__ __launch_bounds__(256) void to_grouped(
    const float* __restrict__ in, unsigned short* __restrict__ gout,
    const float* __restrict__ rois, int* __restrict__ perm)
{
    if (blockIdx.x == 0) {
        __shared__ int cnt[4];
        __shared__ int base[4];
        int t = threadIdx.x;
        if (t < 4) cnt[t] = 0;
        __syncthreads();
        int bb[4], po[4];
        #pragma unroll
        for (int r = 0; r < 4; ++r) {
            int ri = r * 256 + t;
            int b = (int)rois[ri * 5];
            bb[r] = b;
            po[r] = atomicAdd(&cnt[b], 1);
        }
        __syncthreads();
        if (t == 0) {
            int s = 0;
            #pragma unroll
            for (int i = 0; i < 4; ++i) { base[i] = s; s += cnt[i]; }
        }
        __syncthreads();
        #pragma unroll
        for (int r = 0; r < 4; ++r)
            perm[base[bb[r]] + po[r]] = r * 256 + t;
    }

    int idx = blockIdx.x * 256 + threadIdx.x;
    int p  = idx % PLANE;
    int bg = idx / PLANE;
    const float* src = in + (size_t)bg * GSZ * PLANE + p;

    unsigned short tmp[GSZ];
    #pragma unroll
    for (int j = 0; j < GSZ; ++j) {
        float f = __builtin_nontemporal_load(&src[(size_t)j * PLANE]);
        unsigned u = __float_as_uint(f);
        tmp[j] = (unsigned short)((u + 0x7FFFu + ((u >> 16) & 1u)) >> 16);
    }
    uint4* dst = (uint4*)(gout + (size_t)idx * GSZ);
    #pragma unroll
    for (int k = 0; k < 4; ++k) {
        uint4 q;
        __builtin_memcpy(&q, &tmp[k * 8], 16);
        dst[k] = q;
    }
}

__global__ __launch_bounds__(256) void roi_align_grouped(
    const unsigned short* __restrict__ gfeat,
    const float* __restrict__ rois,
    const int* __restrict__ perm,
    float* __restrict__ out)
{
    int nb  = gridDim.x;
    int vb  = (blockIdx.x & 7) * (nb >> 3) + (blockIdx.x >> 3);
    int idx = vb * 256 + threadIdx.x;

    int s      = idx & 3;
    int bin    = (idx >> 2) % PP;
    int n_slot = (idx / (4 * PP)) % N_ROIS;
    int g      = idx / (4 * PP * N_ROIS);
    int n      = perm[n_slot];
    int ph = bin / 7, pw = bin % 7;

    const float* roi = rois + n * 5;
    int   b  = (int)roi[0];
    float x1 = roi[1] * 0.25f - 0.5f;
    float y1 = roi[2] * 0.25f - 0.5f;
    float x2 = roi[3] * 0.25f - 0.5f;
    float y2 = roi[4] * 0.25f - 0.5f;
    float bin_h = (y2 - y1) / 7.0f;
    float bin_w = (x2 - x1) / 7.0f;

    const unsigned short* plane =
        gfeat + (size_t)(b * NG + g) * (size_t)PLANE * GSZ + s * 8;

    int   yy0[2], yy1[2];
    float wy0[2], wy1[2];
    #pragma unroll
    for (int iy = 0; iy < 2; ++iy) {
        float y = y1 + ((float)ph + ((float)iy + 0.5f) * 0.5f) * bin_h;
        float v = (y >= -1.0f && y <= (float)FH) ? 1.0f : 0.0f;
        float yc = fminf(fmaxf(y, 0.0f), (float)(FH - 1));
        int   y0 = (int)yc;
        yy0[iy] = y0;
        yy1[iy] = min(y0 + 1, FH - 1);
        float ly = yc - (float)y0;
        wy1[iy] = ly * v;
        wy0[iy] = (1.0f - ly) * v;
    }
    int   xx0[2], xx1[2];
    float wx0[2], wx1[2];
    #pragma unroll
    for (int ix = 0; ix < 2; ++ix) {
        float x = x1 + ((float)pw + ((float)ix + 0.5f) * 0.5f) * bin_w;
        float v = (x >= -1.0f && x <= (float)FW) ? 1.0f : 0.0f;
        float xc = fminf(fmaxf(x, 0.0f), (float)(FW - 1));
        int   x0 = (int)xc;
        xx0[ix] = x0;
        xx1[ix] = min(x0 + 1, FW - 1);
        float lx = xc - (float)x0;
        wx1[ix] = lx * v;
        wx0[ix] = (1.0f - lx) * v;
    }

    float acc[8] = {0, 0, 0, 0, 0, 0, 0, 0};

    #pragma unroll
    for (int iy = 0; iy < 2; ++iy) {
        const unsigned short* r0 = plane + (size_t)(yy0[iy] * FW) * GSZ;
        const unsigned short* r1 = plane + (size_t)(yy1[iy] * FW) * GSZ;
        #pragma unroll
        for (int ix = 0; ix < 2; ++ix) {
            uint4 qA = *(const uint4*)(r0 + (size_t)xx0[ix] * GSZ);
            uint4 qB = *(const uint4*)(r0 + (size_t)xx1[ix] * GSZ);
            uint4 qC = *(const uint4*)(r1 + (size_t)xx0[ix] * GSZ);
            uint4 qD = *(const uint4*)(r1 + (size_t)xx1[ix] * GSZ);
            fma8q(acc, qA, wy0[iy] * wx0[ix]);
            fma8q(acc, qB, wy0[iy] * wx1[ix]);
            fma8q(acc, qC, wy1[iy] * wx0[ix]);
            fma8q(acc, qD, wy1[iy] * wx1[ix]);
        }
    }

    float* o = out + ((size_t)n * CCH + g * GSZ + s * 8) * PP + bin;
    #pragma unroll
    for (int j = 0; j < 8; ++j)
        __builtin_nontemporal_store(acc[j] * 0.25f, o + j * PP);
}

// ---------------- last-resort fallback (tiny ws) ----------------
__global__ __launch_bounds__(256) void roi_align_fallback(
    const float* __restrict__ feat, const float* __restrict__ rois,
    float* __restrict__ out, int total)
{
    int nb  = gridDim.x;
    int vid = (blockIdx.x & 7) * (nb >> 3) + (blockIdx.x >> 3);
    int idx = vid * 256 + threadIdx.x;
    if (idx >= total) return;
    int pw = idx % 7;
    int ph = (idx / 7) % 7;
    int n  = (idx / 49) & (N_ROIS - 1);
    int c  = idx / (49 * N_ROIS);

    const float* roi = rois + n * 5;
    int   b  = (int)roi[0];
    float x1 = roi[1] * 0.25f - 0.5f;
    float y1 = roi[2] * 0.25f - 0.5f;
    float x2 = roi[3] * 0.25f - 0.5f;
    float y2 = roi[4] * 0.25f - 0.5f;
    float bin_h = (y2 - y1) / 7.0f;
    float bin_w = (x2 - x1) / 7.0f;
    const float* plane = feat + ((size_t)b * CCH + c) * PLANE;

    float acc = 0.0f;
    #pragma unroll
    for (int iy = 0; iy < 2; ++iy) {
        float y = y1 + ((float)ph + ((float)iy + 0.5f) * 0.5f) * bin_h;
        if (y < -1.0f || y > (float)FH) continue;
        float yc = fminf(fmaxf(y, 0.0f), (float)(FH - 1));
        int y0 = (int)yc, y1i = min(y0 + 1, FH - 1);
        float ly = yc - (float)y0, hy = 1.0f - ly;
        #pragma unroll
        for (int ix = 0; ix < 2; ++ix) {
            float x = x1 + ((float)pw + ((float)ix + 0.5f) * 0.5f) * bin_w;
            if (x < -1.0f || x > (float)FW) continue;
            float xc = fminf(fmaxf(x, 0.0f), (float)(FW - 1));
            int x0 = (int)xc, x1i = min(x0 + 1, FW - 1);
            float lx = xc - (float)x0, hx = 1.0f - lx;
            acc += hy * (hx * plane[y0 * FW + x0] + lx * plane[y0 * FW + x1i])
                 + ly * (hx * plane[y1i * FW + x0] + lx * plane[y1i * FW + x1i]);
        }
    }
    out[((size_t)n * CCH + c) * PP + ph * 7 + pw] = acc * 0.25f;
}

extern "C" void kernel_launch(void* const* d_in, const int* in_sizes, int n_in,
                              void* d_out, int out_size, void* d_ws, size_t ws_size,
                              hipStream_t stream)
{
    const float* feat = (const float*)d_in[0];
    const float* rois = (const float*)d_in[1];
    float* out = (float*)d_out;

    const size_t gfeat_bytes = (size_t)4 * NG * PLANE * GSZ * 2;  // 81.92 MB
    const size_t ws_needed = gfeat_bytes + N_ROIS * sizeof(int);

    if (ws_size >= ws_needed) {
        unsigned short* gfeat = (unsigned short*)d_ws;
        int* perm = (int*)((char*)d_ws + gfeat_bytes);

        void* args[5] = { (void*)&feat, (void*)&rois, (void*)&gfeat,
                          (void*)&perm, (void*)&out };
        hipError_t e = hipLaunchCooperativeKernel(
            reinterpret_cast<void*>(fused_roi_align),
            dim3(1024), dim3(256), args, 0, stream);
        if (e != hipSuccess) {
            // cooperative refused: R4 two-kernel path
            to_grouped<<<(4 * NG * PLANE) / 256, 256, 0, stream>>>(feat, gfeat, rois, perm);
            int items = NG * N_ROIS * PP * 4;
            roi_align_grouped<<<items / 256, 256, 0, stream>>>(gfeat, rois, perm, out);
        }
    } else {
        int total = out_size;
        int grid = (total + 255) / 256;
        roi_align_fallback<<<grid, 256, 0, stream>>>(feat, rois, out, total);
    }
}

// Round 14
// 268.934 us; speedup vs baseline: 1.8187x; 1.8187x over previous
//
#include <hip/hip_runtime.h>
#include <hip/hip_bf16.h>

// RoIAlign (avg, aligned=True).
//   input: (4, 256, 200, 200) fp32, rois: (1024, 5) fp32 -> out (1024,256,7,7) fp32
//
// R17 = R15 with one compile fix: __builtin_nontemporal_store needs a clang
// ext_vector_type pointer, not HIP's uint4 struct. Design unchanged:
// R4 two-kernel skeleton (296.2 us measured) + pass 2 as one block per
// (n,g) with LDS-staged COALESCED output stores (kills the measured ~2.4x
// write amplification: 207 vs 133 MB, R11 profile). Gather math bit-identical.

#define CCH 256
#define FH 200
#define FW 200
#define N_ROIS 1024
#define PP 49          // 7*7 bins
#define NG 8           // channel groups (256/32)
#define GSZ 32         // channels per group
#define PLANE (FH*FW)

typedef unsigned int u32x4 __attribute__((ext_vector_type(4)));

// ---------- pass 1: NCHW fp32 -> grouped bf16 (+ fused ROI sort in blk 0) ----------
__global__ __launch_bounds__(256) void to_grouped(
    const float* __restrict__ in, unsigned short* __restrict__ gout,
    const float* __restrict__ rois, int* __restrict__ perm)
{
    if (blockIdx.x == 0) {
        // counting-sort 1024 ROIs by image index (any within-bucket order ok)
        __shared__ int cnt[4];
        __shared__ int base[4];
        int t = threadIdx.x;
        if (t < 4) cnt[t] = 0;
        __syncthreads();
        int bb[4], po[4];
        #pragma unroll
        for (int r = 0; r < 4; ++r) {
            int ri = r * 256 + t;
            int b = (int)rois[ri * 5];
            bb[r] = b;
            po[r] = atomicAdd(&cnt[b], 1);
        }
        __syncthreads();
        if (t == 0) {
            int s = 0;
            #pragma unroll
            for (int i = 0; i < 4; ++i) { base[i] = s; s += cnt[i]; }
        }
        __syncthreads();
        #pragma unroll
        for (int r = 0; r < 4; ++r)
            perm[base[bb[r]] + po[r]] = r * 256 + t;
    }

    int idx = blockIdx.x * 256 + threadIdx.x;   // 4*8*40000 = 1,280,000 exact
    int p  = idx % PLANE;
    int bg = idx / PLANE;                       // b*8+g ; c_base = 32*bg
    const float* src = in + (size_t)bg * GSZ * PLANE + p;

    unsigned short tmp[GSZ];
    #pragma unroll
    for (int j = 0; j < GSZ; ++j) {
        float f = __builtin_nontemporal_load(&src[(size_t)j * PLANE]);
        unsigned u = __float_as_uint(f);
        tmp[j] = (unsigned short)((u + 0x7FFFu + ((u >> 16) & 1u)) >> 16); // RNE
    }
    u32x4* dst = (u32x4*)(gout + (size_t)idx * GSZ);
    #pragma unroll
    for (int k = 0; k < 4; ++k) {
        u32x4 q;
        __builtin_memcpy(&q, &tmp[k * 8], 16);
        dst[k] = q;
    }
}

// ---------- pass 2: gather, one block per (n_slot, g), coalesced stores ----------
__device__ __forceinline__ void fma8q(float* acc, u32x4 q, float w)
{
    unsigned short u[8];
    __builtin_memcpy(u, &q, 16);
    #pragma unroll
    for (int j = 0; j < 8; ++j)
        acc[j] = fmaf(w, __uint_as_float((unsigned)u[j] << 16), acc[j]);
}

__global__ __launch_bounds__(256) void roi_align_v2(
    const unsigned short* __restrict__ gfeat,
    const float* __restrict__ rois,
    const int* __restrict__ perm,
    float* __restrict__ out)
{
    // 8192 blocks. XCD swizzle: vb = (bid&7)*1024 + bid>>3 -> g = vb>>10 = XCD,
    // n_slot = vb&1023 ascending within each XCD (sorted ROIs -> b monotone;
    // working set one (g,b) plane-group = 2.56 MB < 4 MB XCD L2).
    int vb     = (blockIdx.x & 7) * (gridDim.x >> 3) + (blockIdx.x >> 3);
    int g      = vb >> 10;
    int n_slot = vb & 1023;
    int n      = perm[n_slot];
    int t      = threadIdx.x;

    __shared__ float obuf[GSZ * PP];            // 32 ch x 49 bins = 6272 B

    if (t < 4 * PP) {                           // 196 active compute lanes
        int bin = t >> 2;                       // 0..48
        int s   = t & 3;                        // 8-channel slice
        int ph = bin / 7, pw = bin % 7;

        const float* roi = rois + n * 5;
        int   b  = (int)roi[0];
        float x1 = roi[1] * 0.25f - 0.5f;
        float y1 = roi[2] * 0.25f - 0.5f;
        float x2 = roi[3] * 0.25f - 0.5f;
        float y2 = roi[4] * 0.25f - 0.5f;
        float bin_h = (y2 - y1) / 7.0f;
        float bin_w = (x2 - x1) / 7.0f;

        const unsigned short* plane =
            gfeat + (size_t)(b * NG + g) * (size_t)PLANE * GSZ + s * 8;

        // branchless weight-folded validity (bit-identical to R4 math)
        int   yy0[2], yy1[2];
        float wy0[2], wy1[2];
        #pragma unroll
        for (int iy = 0; iy < 2; ++iy) {
            float y = y1 + ((float)ph + ((float)iy + 0.5f) * 0.5f) * bin_h;
            float v = (y >= -1.0f && y <= (float)FH) ? 1.0f : 0.0f;
            float yc = fminf(fmaxf(y, 0.0f), (float)(FH - 1));
            int   y0 = (int)yc;
            yy0[iy] = y0;
            yy1[iy] = min(y0 + 1, FH - 1);
            float ly = yc - (float)y0;
            wy1[iy] = ly * v;
            wy0[iy] = (1.0f - ly) * v;
        }
        int   xx0[2], xx1[2];
        float wx0[2], wx1[2];
        #pragma unroll
        for (int ix = 0; ix < 2; ++ix) {
            float x = x1 + ((float)pw + ((float)ix + 0.5f) * 0.5f) * bin_w;
            float v = (x >= -1.0f && x <= (float)FW) ? 1.0f : 0.0f;
            float xc = fminf(fmaxf(x, 0.0f), (float)(FW - 1));
            int   x0 = (int)xc;
            xx0[ix] = x0;
            xx1[ix] = min(x0 + 1, FW - 1);
            float lx = xc - (float)x0;
            wx1[ix] = lx * v;
            wx0[ix] = (1.0f - lx) * v;
        }

        float acc[8] = {0, 0, 0, 0, 0, 0, 0, 0};

        #pragma unroll
        for (int iy = 0; iy < 2; ++iy) {
            const unsigned short* r0 = plane + (size_t)(yy0[iy] * FW) * GSZ;
            const unsigned short* r1 = plane + (size_t)(yy1[iy] * FW) * GSZ;
            #pragma unroll
            for (int ix = 0; ix < 2; ++ix) {
                u32x4 qA = *(const u32x4*)(r0 + (size_t)xx0[ix] * GSZ);
                u32x4 qB = *(const u32x4*)(r0 + (size_t)xx1[ix] * GSZ);
                u32x4 qC = *(const u32x4*)(r1 + (size_t)xx0[ix] * GSZ);
                u32x4 qD = *(const u32x4*)(r1 + (size_t)xx1[ix] * GSZ);
                fma8q(acc, qA, wy0[iy] * wx0[ix]);
                fma8q(acc, qB, wy0[iy] * wx1[ix]);
                fma8q(acc, qC, wy1[iy] * wx0[ix]);
                fma8q(acc, qD, wy1[iy] * wx1[ix]);
            }
        }

        // obuf[c_local][bin], c_local = s*8+j
        #pragma unroll
        for (int j = 0; j < 8; ++j)
            obuf[(s * 8 + j) * PP + bin] = acc[j] * 0.25f;
    }
    __syncthreads();

    // coalesced streaming store: out[n][g*32 .. g*32+31][0..48] is one
    // contiguous 6272 B region, 16B-aligned. 392 x 16B stores.
    u32x4* dst = (u32x4*)(out + ((size_t)n * CCH + g * GSZ) * PP);
    const u32x4* src = (const u32x4*)obuf;
    for (int k = t; k < (GSZ * PP) / 4; k += 256)
        __builtin_nontemporal_store(src[k], dst + k);
}

// ---------- fallback (R1 kernel) if ws too small ----------
__global__ __launch_bounds__(256) void roi_align_fallback(
    const float* __restrict__ feat, const float* __restrict__ rois,
    float* __restrict__ out, int total)
{
    int nb  = gridDim.x;
    int vid = (blockIdx.x & 7) * (nb >> 3) + (blockIdx.x >> 3);
    int idx = vid * 256 + threadIdx.x;
    if (idx >= total) return;
    int pw = idx % 7;
    int ph = (idx / 7) % 7;
    int n  = (idx / 49) & (N_ROIS - 1);
    int c  = idx / (49 * N_ROIS);

    const float* roi = rois + n * 5;
    int   b  = (int)roi[0];
    float x1 = roi[1] * 0.25f - 0.5f;
    float y1 = roi[2] * 0.25f - 0.5f;
    float x2 = roi[3] * 0.25f - 0.5f;
    float y2 = roi[4] * 0.25f - 0.5f;
    float bin_h = (y2 - y1) / 7.0f;
    float bin_w = (x2 - x1) / 7.0f;
    const float* plane = feat + ((size_t)b * CCH + c) * PLANE;

    float acc = 0.0f;
    #pragma unroll
    for (int iy = 0; iy < 2; ++iy) {
        float y = y1 + ((float)ph + ((float)iy + 0.5f) * 0.5f) * bin_h;
        if (y < -1.0f || y > (float)FH) continue;
        float yc = fminf(fmaxf(y, 0.0f), (float)(FH - 1));
        int y0 = (int)yc, y1i = min(y0 + 1, FH - 1);
        float ly = yc - (float)y0, hy = 1.0f - ly;
        #pragma unroll
        for (int ix = 0; ix < 2; ++ix) {
            float x = x1 + ((float)pw + ((float)ix + 0.5f) * 0.5f) * bin_w;
            if (x < -1.0f || x > (float)FW) continue;
            float xc = fminf(fmaxf(x, 0.0f), (float)(FW - 1));
            int x0 = (int)xc, x1i = min(x0 + 1, FW - 1);
            float lx = xc - (float)x0, hx = 1.0f - lx;
            acc += hy * (hx * plane[y0 * FW + x0] + lx * plane[y0 * FW + x1i])
                 + ly * (hx * plane[y1i * FW + x0] + lx * plane[y1i * FW + x1i]);
        }
    }
    out[((size_t)n * CCH + c) * PP + ph * 7 + pw] = acc * 0.25f;
}

extern "C" void kernel_launch(void* const* d_in, const int* in_sizes, int n_in,
                              void* d_out, int out_size, void* d_ws, size_t ws_size,
                              hipStream_t stream)
{
    const float* feat = (const float*)d_in[0];
    const float* rois = (const float*)d_in[1];
    float* out = (float*)d_out;

    const size_t gfeat_bytes = (size_t)4 * NG * PLANE * GSZ * 2;  // 81.92 MB
    const size_t ws_needed = gfeat_bytes + N_ROIS * sizeof(int);

    if (ws_size >= ws_needed) {
        unsigned short* gfeat = (unsigned short*)d_ws;
        int* perm = (int*)((char*)d_ws + gfeat_bytes);
        to_grouped<<<(4 * NG * PLANE) / 256, 256, 0, stream>>>(feat, gfeat, rois, perm);
        roi_align_v2<<<NG * N_ROIS, 256, 0, stream>>>(gfeat, rois, perm, out);
    } else {
        int total = out_size;
        int grid = (total + 255) / 256;
        roi_align_fallback<<<grid, 256, 0, stream>>>(feat, rois, out, total);
    }
}